// Round 5
// baseline (136.123 us; speedup 1.0000x reference)
//
#include <hip/hip_runtime.h>

#define B_ 4
#define H_ 8
#define LQ_ 256
#define LK_ 256
#define DK_ 64
#define BH_ (B_*H_)           // 32
#define NROWS (BH_*LQ_)       // 8192 rows per projection
#define QT 8                  // q rows per block in fused score kernel

// ---------------- K1: projections qp = q*Wq^T + bq, kp = k*Wk^T + bk ----
// grid 512: blocks [0,256) -> q-proj, [256,512) -> k-proj; 32 rows/block.
// W staged in LDS at stride 68; e = gg + i*8 so the 8 lane-groups read
// banks {4g..4g+3} -> conflict-free (68%32=4; e=gg*8+i would be 8-way).
__global__ __launch_bounds__(256) void proj_kernel(
    const float* __restrict__ qin, const float* __restrict__ kin,
    const float* __restrict__ Wq, const float* __restrict__ bq,
    const float* __restrict__ Wk, const float* __restrict__ bk,
    float* __restrict__ qp, float* __restrict__ kp)
{
    const int which = blockIdx.x >> 8;           // 0 = q, 1 = k
    const int rb    = (blockIdx.x & 255) * 32;   // first row of this block
    const float* in   = which ? kin : qin;
    const float* W    = which ? Wk  : Wq;
    const float* bias = which ? bk  : bq;
    float* out        = which ? kp  : qp;

    __shared__ float in_s[32*68];
    __shared__ float w_s[64*68];
    const int tid = threadIdx.x;

    {
        const float4* g = (const float4*)(in + rb*64);
        #pragma unroll
        for (int p = 0; p < 2; ++p) {
            int f = tid + p*256;
            float4 x = g[f];
            *(float4*)&in_s[(f>>4)*68 + (f&15)*4] = x;
        }
    }
    {
        const float4* g = (const float4*)W;
        #pragma unroll
        for (int p = 0; p < 4; ++p) {
            int f = tid + p*256;
            float4 x = g[f];
            *(float4*)&w_s[(f>>4)*68 + (f&15)*4] = x;
        }
    }
    __syncthreads();

    const int r  = tid >> 3;                     // 0..31 row
    const int gg = tid & 7;                      // e = gg + i*8
    float acc[8];
    #pragma unroll
    for (int i = 0; i < 8; ++i) acc[i] = 0.f;

    #pragma unroll
    for (int j = 0; j < 16; ++j) {
        float4 x = *(const float4*)&in_s[r*68 + j*4];   // 8-lane broadcast
        #pragma unroll
        for (int i = 0; i < 8; ++i) {
            float4 w = *(const float4*)&w_s[(gg + i*8)*68 + j*4]; // cf-free
            acc[i] = fmaf(w.x, x.x, acc[i]);
            acc[i] = fmaf(w.y, x.y, acc[i]);
            acc[i] = fmaf(w.z, x.z, acc[i]);
            acc[i] = fmaf(w.w, x.w, acc[i]);
        }
    }
    float* orow = out + (rb + r)*64;
    #pragma unroll
    for (int i = 0; i < 8; ++i) {
        const int e = gg + i*8;
        orow[e] = acc[i] + bias[e];
    }
}

// ---------------- K2: scores + softmax + attn-write + PV (fused) --------
// grid = BH_ * (LQ_/QT) = 32*32 = 1024 blocks = EXACTLY 4 blocks/CU, which
// co-resides at any VGPR <= 128 -> one balanced round, no straggler tail
// (R4: 2048 blocks at 6-resident ran as 6+2 rounds; the 2-block tail with
// 2 waves/SIMD was latency-crippled -> 62 us, occupancy 28%).
// Thread t owns k = t. score = vs_b + sum(vs)
//   - 2 * sum_d vs[d] * rcp(exp2(C2*qp_d + C2*kp_d) + 1),  C2 = 2*log2(e).
// kp processed in QUARTERS (kr[4]=16 VGPRs live), unroll 1 so loads can't be
// hoisted (R1: 256-VGPR spill; R2: forced-64 spill -> 1.1 GB scratch).
// No max-subtraction: |score| <= |vs_b|+sum|vs| <= ~8.2 -> exp safe in fp32.
// PV wave-parallel (R5): wave w owns k-slice [64w,64w+64): 64 coalesced
// 256 B v loads + 512 FMA; a_s read as wave-uniform b128 broadcasts;
// partials reduced via LDS. (R4's per-thread 256 scalar-load PV cost ~22 us.)
__global__ __launch_bounds__(256) void score_softmax_pv_kernel(
    const float* __restrict__ qp, const float* __restrict__ kp,
    const float* __restrict__ vs_w, const float* __restrict__ vs_b,
    const float* __restrict__ v,
    float* __restrict__ attn, float* __restrict__ out)
{
    const int bh = blockIdx.x >> 5;          // LQ_/QT = 32 chunks per bh
    const int qt = blockIdx.x & 31;
    const int t  = threadIdx.x;
    const int lane = t & 63, wid = t >> 6;

    const float C2  = 2.8853900817779268f;   // 2*log2(e)
    const float L2E = 1.4426950408889634f;

    __shared__ float qp_s[QT*64];            // 2 KB, pre-scaled by C2
    __shared__ float vs_s[64];
    __shared__ float reds[QT][4];
    __shared__ float a_s[QT*256];            // 8 KB normalized attn tile
    __shared__ float p_s[4*QT*64];           // 8 KB PV partials (per wave)

    if (t < QT*16) {
        float4 x = ((const float4*)(qp + (bh*LQ_ + qt*QT)*64))[t];
        x.x *= C2; x.y *= C2; x.z *= C2; x.w *= C2;
        ((float4*)qp_s)[t] = x;
    } else if (t < QT*16 + 64) {
        vs_s[t - QT*16] = vs_w[t - QT*16];
    }
    __syncthreads();

    // base = vs_b + sum(vs)   (LDS broadcast reads)
    float S = vs_b[0];
    #pragma unroll
    for (int j = 0; j < 16; ++j) {
        float4 w = *(const float4*)&vs_s[j*4];
        S += (w.x + w.y) + (w.z + w.w);
    }

    const float4* kg = (const float4*)(kp + (bh*LK_ + t)*64);

    float sc[QT];
    #pragma unroll
    for (int q = 0; q < QT; ++q) sc[q] = 0.f;

    #pragma unroll 1
    for (int quar = 0; quar < 4; ++quar) {
        float4 kr[4];                        // 16 VGPRs live
        #pragma unroll
        for (int j = 0; j < 4; ++j) {
            float4 kv = kg[quar*4 + j];
            kr[j].x = kv.x*C2; kr[j].y = kv.y*C2;
            kr[j].z = kv.z*C2; kr[j].w = kv.w*C2;
        }
        #pragma unroll
        for (int q = 0; q < QT; ++q) {
            float a0 = 0.f, a1 = 0.f;
            #pragma unroll
            for (int j = 0; j < 4; ++j) {
                float4 qv = *(const float4*)&qp_s[q*64 + quar*16 + j*4]; // bcast
                float4 wv = *(const float4*)&vs_s[quar*16 + j*4];        // bcast
                float4 kv = kr[j];
                a0 = fmaf(wv.x, __builtin_amdgcn_rcpf(__builtin_amdgcn_exp2f(qv.x+kv.x)+1.f), a0);
                a1 = fmaf(wv.y, __builtin_amdgcn_rcpf(__builtin_amdgcn_exp2f(qv.y+kv.y)+1.f), a1);
                a0 = fmaf(wv.z, __builtin_amdgcn_rcpf(__builtin_amdgcn_exp2f(qv.z+kv.z)+1.f), a0);
                a1 = fmaf(wv.w, __builtin_amdgcn_rcpf(__builtin_amdgcn_exp2f(qv.w+kv.w)+1.f), a1);
            }
            sc[q] += a0 + a1;
        }
    }

    // p = exp(score); sum over k (no max subtraction; scores bounded)
    float p[QT];
    #pragma unroll
    for (int q = 0; q < QT; ++q) {
        p[q] = __builtin_amdgcn_exp2f((S - 2.f*sc[q]) * L2E);
        float s = p[q];
        #pragma unroll
        for (int off = 32; off; off >>= 1) s += __shfl_xor(s, off, 64);
        if (lane == 0) reds[q][wid] = s;
    }
    __syncthreads();
    #pragma unroll
    for (int q = 0; q < QT; ++q) {
        float s = (reds[q][0] + reds[q][1]) + (reds[q][2] + reds[q][3]);
        float a = p[q] * __builtin_amdgcn_rcpf(s);
        attn[(bh*LQ_ + qt*QT + q)*LK_ + t] = a;   // coalesced global
        a_s[q*256 + t] = a;                       // stride-1: conflict-free
    }
    __syncthreads();

    // PV: wave wid owns k in [wid*64, wid*64+64), lane = d.
    // v loads: 64 lanes x 4 B contiguous = 256 B/instr, L2-resident (64 KB/bh).
    // a_s reads: wave-uniform address -> b128 broadcast, conflict-free.
    {
        float acc[QT];
        #pragma unroll
        for (int q = 0; q < QT; ++q) acc[q] = 0.f;
        const float* vb = v + (bh*LK_ + wid*64)*DK_ + lane;
        #pragma unroll 2
        for (int k4 = 0; k4 < 16; ++k4) {
            float v0 = vb[(k4*4+0)*64];
            float v1 = vb[(k4*4+1)*64];
            float v2 = vb[(k4*4+2)*64];
            float v3 = vb[(k4*4+3)*64];
            #pragma unroll
            for (int q = 0; q < QT; ++q) {
                float4 a4 = *(const float4*)&a_s[q*256 + wid*64 + k4*4];
                acc[q] = fmaf(a4.x, v0, acc[q]);
                acc[q] = fmaf(a4.y, v1, acc[q]);
                acc[q] = fmaf(a4.z, v2, acc[q]);
                acc[q] = fmaf(a4.w, v3, acc[q]);
            }
        }
        #pragma unroll
        for (int q = 0; q < QT; ++q) p_s[wid*512 + q*64 + lane] = acc[q];
    }
    __syncthreads();
    // cross-wave reduce + store: 512 outputs, contiguous in out.
    {
        float* ob = out + (bh*LQ_ + qt*QT)*DK_;
        #pragma unroll
        for (int h = 0; h < 2; ++h) {
            int idx = t + h*256;
            float s = (p_s[idx] + p_s[512 + idx]) + (p_s[1024 + idx] + p_s[1536 + idx]);
            ob[idx] = s;                          // coalesced
        }
    }
}

extern "C" void kernel_launch(void* const* d_in, const int* in_sizes, int n_in,
                              void* d_out, int out_size, void* d_ws, size_t ws_size,
                              hipStream_t stream) {
    const float* q    = (const float*)d_in[0];
    const float* k    = (const float*)d_in[1];
    const float* v    = (const float*)d_in[2];
    const float* Wq_w = (const float*)d_in[3];
    const float* Wq_b = (const float*)d_in[4];
    const float* Wk_w = (const float*)d_in[5];
    const float* Wk_b = (const float*)d_in[6];
    const float* vs_w = (const float*)d_in[7];
    const float* vs_b = (const float*)d_in[8];

    float* out  = (float*)d_out;                      // [B,H,LQ,DK]
    float* attn = out + B_*H_*LQ_*DK_;                // [B,H,LQ,LK]
    float* qp   = (float*)d_ws;                       // 2 MB
    float* kp   = qp + NROWS*64;                      // 2 MB

    proj_kernel<<<512, 256, 0, stream>>>(q, k, Wq_w, Wq_b, Wk_w, Wk_b, qp, kp);
    score_softmax_pv_kernel<<<BH_*(LQ_/QT), 256, 0, stream>>>(
        qp, kp, vs_w, vs_b, v, attn, out);
}

// Round 6
// 115.240 us; speedup vs baseline: 1.1812x; 1.1812x over previous
//
#include <hip/hip_runtime.h>

#define B_ 4
#define H_ 8
#define LQ_ 256
#define LK_ 256
#define DK_ 64
#define BH_ (B_*H_)           // 32
#define NROWS (BH_*LQ_)       // 8192 rows per projection
#define QT 4                  // q rows per block in fused score kernel

// ---------------- K1: qp = C2*(q*Wq^T + bq), kp = C2*(k*Wk^T + bk) ------
// C2 = 2*log2(e) is FOLDED here (qp/kp are internal ws buffers, only K2
// reads them): removes the scale multiplies + 8 live VGPRs from K2's loop.
// grid 512: blocks [0,256) -> q-proj, [256,512) -> k-proj; 32 rows/block.
// W staged in LDS at stride 68; e = gg + i*8 -> conflict-free reads.
__global__ __launch_bounds__(256) void proj_kernel(
    const float* __restrict__ qin, const float* __restrict__ kin,
    const float* __restrict__ Wq, const float* __restrict__ bq,
    const float* __restrict__ Wk, const float* __restrict__ bk,
    float* __restrict__ qp, float* __restrict__ kp)
{
    const int which = blockIdx.x >> 8;           // 0 = q, 1 = k
    const int rb    = (blockIdx.x & 255) * 32;
    const float* in   = which ? kin : qin;
    const float* W    = which ? Wk  : Wq;
    const float* bias = which ? bk  : bq;
    float* out        = which ? kp  : qp;

    __shared__ float in_s[32*68];
    __shared__ float w_s[64*68];
    const int tid = threadIdx.x;

    {
        const float4* g = (const float4*)(in + rb*64);
        #pragma unroll
        for (int p = 0; p < 2; ++p) {
            int f = tid + p*256;
            float4 x = g[f];
            *(float4*)&in_s[(f>>4)*68 + (f&15)*4] = x;
        }
    }
    {
        const float4* g = (const float4*)W;
        #pragma unroll
        for (int p = 0; p < 4; ++p) {
            int f = tid + p*256;
            float4 x = g[f];
            *(float4*)&w_s[(f>>4)*68 + (f&15)*4] = x;
        }
    }
    __syncthreads();

    const int r  = tid >> 3;                     // 0..31 row
    const int gg = tid & 7;                      // e = gg + i*8
    float acc[8];
    #pragma unroll
    for (int i = 0; i < 8; ++i) acc[i] = 0.f;

    #pragma unroll
    for (int j = 0; j < 16; ++j) {
        float4 x = *(const float4*)&in_s[r*68 + j*4];
        #pragma unroll
        for (int i = 0; i < 8; ++i) {
            float4 w = *(const float4*)&w_s[(gg + i*8)*68 + j*4];
            acc[i] = fmaf(w.x, x.x, acc[i]);
            acc[i] = fmaf(w.y, x.y, acc[i]);
            acc[i] = fmaf(w.z, x.z, acc[i]);
            acc[i] = fmaf(w.w, x.w, acc[i]);
        }
    }
    const float C2 = 2.8853900817779268f;        // 2*log2(e)
    float* orow = out + (rb + r)*64;
    #pragma unroll
    for (int i = 0; i < 8; ++i) {
        const int e = gg + i*8;
        orow[e] = (acc[i] + bias[e]) * C2;
    }
}

// ---------------- K2: scores + softmax + attn-write + PV (fused) --------
// grid = BH_*(LQ_/QT) = 2048 blocks, 256 thr. VGPR TIERS ARE COARSE (m69:
// waves/SIMD = 8/4/2 at vgpr <=64 / <=128 / <=256). Target <=64 -> 8 blocks/CU
// -> grid 2048 is ONE fully-resident round (R5: vgpr 148 hit the 2-wave tier,
// occupancy 10%; R4: vgpr 80 = 4-wave tier, VALUBusy 48% from exposed kp
// load latency under unroll-1).
// Thread t owns k = t; qp/kp arrive PRE-SCALED by C2 from K1.
// score = vs_b + sum(vs) - 2*sum_d vs[d]*rcp(exp2(qp_d + kp_d) + 1)
// kp consumed in EIGHTHS with double-buffered prefetch (k0,k1 | kn0,kn1 =
// 16 VGPRs): next eighth's global loads are in flight during compute, so L2
// latency (~200 cy) is hidden instead of serialized 4x per thread (R4 bug).
// No max-subtraction: |score| <= |vs_b|+sum|vs| <= ~8.2 -> exp safe in fp32.
// PV wave-parallel: wave wid owns k-slice [64w,64w+64), lane = d; coalesced
// 256 B v loads; a_s read as wave-uniform b128 broadcasts; LDS reduce.
__global__ __launch_bounds__(256) void score_softmax_pv_kernel(
    const float* __restrict__ qp, const float* __restrict__ kp,
    const float* __restrict__ vs_w, const float* __restrict__ vs_b,
    const float* __restrict__ v,
    float* __restrict__ attn, float* __restrict__ out)
{
    const int bh = blockIdx.x >> 6;          // LQ_/QT = 64 chunks per bh
    const int qt = blockIdx.x & 63;
    const int t  = threadIdx.x;
    const int lane = t & 63, wid = t >> 6;

    const float L2E = 1.4426950408889634f;

    __shared__ float qp_s[QT*64];            // 1 KB (pre-scaled by C2)
    __shared__ float vs_s[64];
    __shared__ float reds[QT][4];
    __shared__ float a_s[QT*256];            // 4 KB normalized attn tile
    __shared__ float p_s[4*QT*64];           // 4 KB PV partials

    // prefetch eighth 0 of this thread's kp row BEFORE the staging barrier
    const float4* kg = (const float4*)(kp + (bh*LK_ + t)*64);
    float4 k0 = kg[0], k1 = kg[1];

    if (t < QT*16) {
        ((float4*)qp_s)[t] = ((const float4*)(qp + (bh*LQ_ + qt*QT)*64))[t];
    } else if (t < QT*16 + 64) {
        vs_s[t - QT*16] = vs_w[t - QT*16];   // raw vs (not scaled)
    }
    __syncthreads();

    // base = vs_b + sum(vs)
    float S = vs_b[0];
    #pragma unroll
    for (int j = 0; j < 16; ++j) {
        float4 w = *(const float4*)&vs_s[j*4];
        S += (w.x + w.y) + (w.z + w.w);
    }

    float sc[QT] = {0.f, 0.f, 0.f, 0.f};
    #pragma unroll 1
    for (int e8 = 0; e8 < 8; ++e8) {
        const int nx = ((e8+1) & 7) * 2;     // wrap at end: in-bounds, harmless
        float4 kn0 = kg[nx], kn1 = kg[nx+1]; // prefetch next eighth (in flight)
        #pragma unroll
        for (int q = 0; q < QT; ++q) {
            float a0 = 0.f, a1 = 0.f;
            float4 qv0 = *(const float4*)&qp_s[q*64 + e8*8];      // bcast
            float4 wv0 = *(const float4*)&vs_s[e8*8];             // bcast
            a0 = fmaf(wv0.x, __builtin_amdgcn_rcpf(__builtin_amdgcn_exp2f(qv0.x+k0.x)+1.f), a0);
            a1 = fmaf(wv0.y, __builtin_amdgcn_rcpf(__builtin_amdgcn_exp2f(qv0.y+k0.y)+1.f), a1);
            a0 = fmaf(wv0.z, __builtin_amdgcn_rcpf(__builtin_amdgcn_exp2f(qv0.z+k0.z)+1.f), a0);
            a1 = fmaf(wv0.w, __builtin_amdgcn_rcpf(__builtin_amdgcn_exp2f(qv0.w+k0.w)+1.f), a1);
            float4 qv1 = *(const float4*)&qp_s[q*64 + e8*8 + 4];
            float4 wv1 = *(const float4*)&vs_s[e8*8 + 4];
            a0 = fmaf(wv1.x, __builtin_amdgcn_rcpf(__builtin_amdgcn_exp2f(qv1.x+k1.x)+1.f), a0);
            a1 = fmaf(wv1.y, __builtin_amdgcn_rcpf(__builtin_amdgcn_exp2f(qv1.y+k1.y)+1.f), a1);
            a0 = fmaf(wv1.z, __builtin_amdgcn_rcpf(__builtin_amdgcn_exp2f(qv1.z+k1.z)+1.f), a0);
            a1 = fmaf(wv1.w, __builtin_amdgcn_rcpf(__builtin_amdgcn_exp2f(qv1.w+k1.w)+1.f), a1);
            sc[q] += a0 + a1;
        }
        k0 = kn0; k1 = kn1;
    }

    // p = exp(score); sum over k (no max subtraction; scores bounded)
    float p[QT];
    #pragma unroll
    for (int q = 0; q < QT; ++q) {
        p[q] = __builtin_amdgcn_exp2f((S - 2.f*sc[q]) * L2E);
        float s = p[q];
        #pragma unroll
        for (int off = 32; off; off >>= 1) s += __shfl_xor(s, off, 64);
        if (lane == 0) reds[q][wid] = s;
    }
    __syncthreads();
    #pragma unroll
    for (int q = 0; q < QT; ++q) {
        float s = (reds[q][0] + reds[q][1]) + (reds[q][2] + reds[q][3]);
        float a = p[q] * __builtin_amdgcn_rcpf(s);
        attn[(bh*LQ_ + qt*QT + q)*LK_ + t] = a;   // coalesced global
        a_s[q*256 + t] = a;                       // stride-1: conflict-free
    }
    __syncthreads();

    // PV: wave wid owns k in [wid*64, wid*64+64), lane = d.
    {
        float acc[QT] = {0.f, 0.f, 0.f, 0.f};
        const float* vb = v + (bh*LK_ + wid*64)*DK_ + lane;
        #pragma unroll 2
        for (int k4 = 0; k4 < 16; ++k4) {
            float v0 = vb[(k4*4+0)*64];
            float v1 = vb[(k4*4+1)*64];
            float v2 = vb[(k4*4+2)*64];
            float v3 = vb[(k4*4+3)*64];
            #pragma unroll
            for (int q = 0; q < QT; ++q) {
                float4 a4 = *(const float4*)&a_s[q*256 + wid*64 + k4*4]; // bcast
                acc[q] = fmaf(a4.x, v0, acc[q]);
                acc[q] = fmaf(a4.y, v1, acc[q]);
                acc[q] = fmaf(a4.z, v2, acc[q]);
                acc[q] = fmaf(a4.w, v3, acc[q]);
            }
        }
        #pragma unroll
        for (int q = 0; q < QT; ++q) p_s[wid*256 + q*64 + lane] = acc[q];
    }
    __syncthreads();
    // cross-wave reduce + store: 256 outputs (QT x 64), one per thread.
    {
        float s = (p_s[t] + p_s[256 + t]) + (p_s[512 + t] + p_s[768 + t]);
        out[(bh*LQ_ + qt*QT)*DK_ + t] = s;        // coalesced
    }
}

extern "C" void kernel_launch(void* const* d_in, const int* in_sizes, int n_in,
                              void* d_out, int out_size, void* d_ws, size_t ws_size,
                              hipStream_t stream) {
    const float* q    = (const float*)d_in[0];
    const float* k    = (const float*)d_in[1];
    const float* v    = (const float*)d_in[2];
    const float* Wq_w = (const float*)d_in[3];
    const float* Wq_b = (const float*)d_in[4];
    const float* Wk_w = (const float*)d_in[5];
    const float* Wk_b = (const float*)d_in[6];
    const float* vs_w = (const float*)d_in[7];
    const float* vs_b = (const float*)d_in[8];

    float* out  = (float*)d_out;                      // [B,H,LQ,DK]
    float* attn = out + B_*H_*LQ_*DK_;                // [B,H,LQ,LK]
    float* qp   = (float*)d_ws;                       // 2 MB (C2-scaled)
    float* kp   = qp + NROWS*64;                      // 2 MB (C2-scaled)

    proj_kernel<<<512, 256, 0, stream>>>(q, k, Wq_w, Wq_b, Wk_w, Wk_b, qp, kp);
    score_softmax_pv_kernel<<<BH_*(LQ_/QT), 256, 0, stream>>>(
        qp, kp, vs_w, vs_b, v, attn, out);
}

// Round 7
// 109.048 us; speedup vs baseline: 1.2483x; 1.0568x over previous
//
#include <hip/hip_runtime.h>

#define B_ 4
#define H_ 8
#define LQ_ 256
#define LK_ 256
#define DK_ 64
#define BH_ (B_*H_)           // 32
#define NROWS (BH_*LQ_)       // 8192 rows per projection
#define QT 4                  // q rows per block in fused score kernel

// ---------------- K1: EQ = exp2(C2*(q*Wq^T+bq)), EK = exp2(C2*(k*Wk^T+bk))
// KEY FACTORIZATION (R7): exp2(C2*(qp+kp)) = exp2(C2*qp)*exp2(C2*kp), so
// the LQ*LK*DK = 134M exponentials of the score loop collapse to
// (LQ+LK)*DK = 0.5M computed HERE, amortized 256x. K2's inner loop becomes
// exp-free: tanh term = rcp(EQ*EK + 1).  C2 = 2*log2(e).
// grid 512: blocks [0,256) -> q-proj, [256,512) -> k-proj; 32 rows/block.
// W staged in LDS at stride 68; e = gg + i*8 -> conflict-free reads.
__global__ __launch_bounds__(256) void proj_kernel(
    const float* __restrict__ qin, const float* __restrict__ kin,
    const float* __restrict__ Wq, const float* __restrict__ bq,
    const float* __restrict__ Wk, const float* __restrict__ bk,
    float* __restrict__ qp, float* __restrict__ kp)
{
    const int which = blockIdx.x >> 8;           // 0 = q, 1 = k
    const int rb    = (blockIdx.x & 255) * 32;
    const float* in   = which ? kin : qin;
    const float* W    = which ? Wk  : Wq;
    const float* bias = which ? bk  : bq;
    float* out        = which ? kp  : qp;

    __shared__ float in_s[32*68];
    __shared__ float w_s[64*68];
    const int tid = threadIdx.x;

    {
        const float4* g = (const float4*)(in + rb*64);
        #pragma unroll
        for (int p = 0; p < 2; ++p) {
            int f = tid + p*256;
            float4 x = g[f];
            *(float4*)&in_s[(f>>4)*68 + (f&15)*4] = x;
        }
    }
    {
        const float4* g = (const float4*)W;
        #pragma unroll
        for (int p = 0; p < 4; ++p) {
            int f = tid + p*256;
            float4 x = g[f];
            *(float4*)&w_s[(f>>4)*68 + (f&15)*4] = x;
        }
    }
    __syncthreads();

    const int r  = tid >> 3;                     // 0..31 row
    const int gg = tid & 7;                      // e = gg + i*8
    float acc[8];
    #pragma unroll
    for (int i = 0; i < 8; ++i) acc[i] = 0.f;

    #pragma unroll
    for (int j = 0; j < 16; ++j) {
        float4 x = *(const float4*)&in_s[r*68 + j*4];
        #pragma unroll
        for (int i = 0; i < 8; ++i) {
            float4 w = *(const float4*)&w_s[(gg + i*8)*68 + j*4];
            acc[i] = fmaf(w.x, x.x, acc[i]);
            acc[i] = fmaf(w.y, x.y, acc[i]);
            acc[i] = fmaf(w.z, x.z, acc[i]);
            acc[i] = fmaf(w.w, x.w, acc[i]);
        }
    }
    const float C2 = 2.8853900817779268f;        // 2*log2(e)
    float* orow = out + (rb + r)*64;
    #pragma unroll
    for (int i = 0; i < 8; ++i) {
        const int e = gg + i*8;
        orow[e] = __builtin_amdgcn_exp2f((acc[i] + bias[e]) * C2);
    }
}

// ---------------- K2: scores + softmax + attn-write + PV (fused) --------
// grid = BH_*(LQ_/QT) = 2048 blocks, 256 thr. VGPR tiers are coarse (m69:
// waves/SIMD = 8/4/2 at vgpr <=64/<=128/<=256): target <=64 -> 8 blocks/CU
// -> grid 2048 is ONE fully-resident round (R6 landed vgpr=60; keep it).
// Thread t owns k = t. qp/kp hold EQ/EK = e^{2*proj} from K1.
// score = vs_b + sum(vs) - 2*sum_d vs[d]*rcp(EQ_d*EK_d + 1)
//   -> per element: fmaf(EQ,EK,1) + rcp + fmaf = 3 instr, 1 trans (was 5/2;
//      the exp factorization in K1 removed all in-loop exponentials).
// EK consumed in EIGHTHS with double-buffered prefetch (k0,k1|kn0,kn1 =
// 16 VGPRs live; R1: 256-vgpr spill, R2: forced-64 spill taught us this).
// No max-subtraction: |score| <= |vs_b|+sum|vs| <= ~8.2 -> exp safe in fp32.
// Saturation is exact: EQ*EK -> inf => rcp -> 0 => tanh -> +1; -> 0 => -1.
// PV wave-parallel: wave wid owns k-slice [64w,64w+64), lane = d; coalesced
// 256 B v loads; a_s read as wave-uniform b128 broadcasts; LDS reduce.
__global__ __launch_bounds__(256) void score_softmax_pv_kernel(
    const float* __restrict__ qp, const float* __restrict__ kp,
    const float* __restrict__ vs_w, const float* __restrict__ vs_b,
    const float* __restrict__ v,
    float* __restrict__ attn, float* __restrict__ out)
{
    const int bh = blockIdx.x >> 6;          // LQ_/QT = 64 chunks per bh
    const int qt = blockIdx.x & 63;
    const int t  = threadIdx.x;
    const int lane = t & 63, wid = t >> 6;

    const float L2E = 1.4426950408889634f;

    __shared__ float qp_s[QT*64];            // 1 KB (EQ values)
    __shared__ float vs_s[64];
    __shared__ float reds[QT][4];
    __shared__ float a_s[QT*256];            // 4 KB normalized attn tile
    __shared__ float p_s[4*QT*64];           // 4 KB PV partials

    // prefetch eighth 0 of this thread's EK row BEFORE the staging barrier
    const float4* kg = (const float4*)(kp + (bh*LK_ + t)*64);
    float4 k0 = kg[0], k1 = kg[1];

    if (t < QT*16) {
        ((float4*)qp_s)[t] = ((const float4*)(qp + (bh*LQ_ + qt*QT)*64))[t];
    } else if (t < QT*16 + 64) {
        vs_s[t - QT*16] = vs_w[t - QT*16];
    }
    __syncthreads();

    // base = vs_b + sum(vs)
    float S = vs_b[0];
    #pragma unroll
    for (int j = 0; j < 16; ++j) {
        float4 w = *(const float4*)&vs_s[j*4];
        S += (w.x + w.y) + (w.z + w.w);
    }

    float sc[QT] = {0.f, 0.f, 0.f, 0.f};
    #pragma unroll 1
    for (int e8 = 0; e8 < 8; ++e8) {
        const int nx = ((e8+1) & 7) * 2;     // wrap at end: in-bounds, harmless
        float4 kn0 = kg[nx], kn1 = kg[nx+1]; // prefetch next eighth (in flight)
        #pragma unroll
        for (int q = 0; q < QT; ++q) {
            float a0 = 0.f, a1 = 0.f;
            float4 qv0 = *(const float4*)&qp_s[q*64 + e8*8];      // bcast
            float4 wv0 = *(const float4*)&vs_s[e8*8];             // bcast
            a0 = fmaf(wv0.x, __builtin_amdgcn_rcpf(fmaf(qv0.x, k0.x, 1.f)), a0);
            a1 = fmaf(wv0.y, __builtin_amdgcn_rcpf(fmaf(qv0.y, k0.y, 1.f)), a1);
            a0 = fmaf(wv0.z, __builtin_amdgcn_rcpf(fmaf(qv0.z, k0.z, 1.f)), a0);
            a1 = fmaf(wv0.w, __builtin_amdgcn_rcpf(fmaf(qv0.w, k0.w, 1.f)), a1);
            float4 qv1 = *(const float4*)&qp_s[q*64 + e8*8 + 4];
            float4 wv1 = *(const float4*)&vs_s[e8*8 + 4];
            a0 = fmaf(wv1.x, __builtin_amdgcn_rcpf(fmaf(qv1.x, k1.x, 1.f)), a0);
            a1 = fmaf(wv1.y, __builtin_amdgcn_rcpf(fmaf(qv1.y, k1.y, 1.f)), a1);
            a0 = fmaf(wv1.z, __builtin_amdgcn_rcpf(fmaf(qv1.z, k1.z, 1.f)), a0);
            a1 = fmaf(wv1.w, __builtin_amdgcn_rcpf(fmaf(qv1.w, k1.w, 1.f)), a1);
            sc[q] += a0 + a1;
        }
        k0 = kn0; k1 = kn1;
    }

    // p = exp(score); sum over k (no max subtraction; scores bounded)
    float p[QT];
    #pragma unroll
    for (int q = 0; q < QT; ++q) {
        p[q] = __builtin_amdgcn_exp2f((S - 2.f*sc[q]) * L2E);
        float s = p[q];
        #pragma unroll
        for (int off = 32; off; off >>= 1) s += __shfl_xor(s, off, 64);
        if (lane == 0) reds[q][wid] = s;
    }
    __syncthreads();
    #pragma unroll
    for (int q = 0; q < QT; ++q) {
        float s = (reds[q][0] + reds[q][1]) + (reds[q][2] + reds[q][3]);
        float a = p[q] * __builtin_amdgcn_rcpf(s);
        attn[(bh*LQ_ + qt*QT + q)*LK_ + t] = a;   // coalesced global
        a_s[q*256 + t] = a;                       // stride-1: conflict-free
    }
    __syncthreads();

    // PV: wave wid owns k in [wid*64, wid*64+64), lane = d.
    {
        float acc[QT] = {0.f, 0.f, 0.f, 0.f};
        const float* vb = v + (bh*LK_ + wid*64)*DK_ + lane;
        #pragma unroll 2
        for (int k4 = 0; k4 < 16; ++k4) {
            float v0 = vb[(k4*4+0)*64];
            float v1 = vb[(k4*4+1)*64];
            float v2 = vb[(k4*4+2)*64];
            float v3 = vb[(k4*4+3)*64];
            #pragma unroll
            for (int q = 0; q < QT; ++q) {
                float4 a4 = *(const float4*)&a_s[q*256 + wid*64 + k4*4]; // bcast
                acc[q] = fmaf(a4.x, v0, acc[q]);
                acc[q] = fmaf(a4.y, v1, acc[q]);
                acc[q] = fmaf(a4.z, v2, acc[q]);
                acc[q] = fmaf(a4.w, v3, acc[q]);
            }
        }
        #pragma unroll
        for (int q = 0; q < QT; ++q) p_s[wid*256 + q*64 + lane] = acc[q];
    }
    __syncthreads();
    // cross-wave reduce + store: 256 outputs (QT x 64), one per thread.
    {
        float s = (p_s[t] + p_s[256 + t]) + (p_s[512 + t] + p_s[768 + t]);
        out[(bh*LQ_ + qt*QT)*DK_ + t] = s;        // coalesced
    }
}

extern "C" void kernel_launch(void* const* d_in, const int* in_sizes, int n_in,
                              void* d_out, int out_size, void* d_ws, size_t ws_size,
                              hipStream_t stream) {
    const float* q    = (const float*)d_in[0];
    const float* k    = (const float*)d_in[1];
    const float* v    = (const float*)d_in[2];
    const float* Wq_w = (const float*)d_in[3];
    const float* Wq_b = (const float*)d_in[4];
    const float* Wk_w = (const float*)d_in[5];
    const float* Wk_b = (const float*)d_in[6];
    const float* vs_w = (const float*)d_in[7];
    const float* vs_b = (const float*)d_in[8];

    float* out  = (float*)d_out;                      // [B,H,LQ,DK]
    float* attn = out + B_*H_*LQ_*DK_;                // [B,H,LQ,LK]
    float* qp   = (float*)d_ws;                       // 2 MB (EQ = e^{2qp})
    float* kp   = qp + NROWS*64;                      // 2 MB (EK = e^{2kp})

    proj_kernel<<<512, 256, 0, stream>>>(q, k, Wq_w, Wq_b, Wk_w, Wk_b, qp, kp);
    score_softmax_pv_kernel<<<BH_*(LQ_/QT), 256, 0, stream>>>(
        qp, kp, vs_w, vs_b, v, attn, out);
}